// Round 1
// baseline (305.065 us; speedup 1.0000x reference)
//
#include <hip/hip_runtime.h>

#define WS 7
#define BB 8
#define HH 384
#define WW 384
#define PP 377          // HH - WS
#define NC 48           // WS*WS - 1
#define NTOT (BB*HH*WW) // 1,179,648

// M[n][k] = (k==0) ? 1 : 2*cos(pi*(2n+1)*k/14)
__constant__ float d_M[7][7] = {
    { 1.0f,  1.9498558244f,  1.8019377358f,  1.5636629649f,  1.2469796037f,  0.8677674782f,  0.4450418679f },
    { 1.0f,  1.5636629649f,  0.4450418679f, -0.8677674782f, -1.8019377358f, -1.9498558244f, -1.2469796037f },
    { 1.0f,  0.8677674782f, -1.2469796037f, -1.9498558244f, -0.4450418679f,  1.5636629649f,  1.8019377358f },
    { 1.0f,  0.0f,          -2.0f,           0.0f,           2.0f,           0.0f,          -2.0f          },
    { 1.0f, -0.8677674782f, -1.2469796037f,  1.9498558244f, -0.4450418679f, -1.5636629649f,  1.8019377358f },
    { 1.0f, -1.5636629649f,  0.4450418679f,  0.8677674782f, -1.8019377358f,  1.9498558244f, -1.2469796037f },
    { 1.0f, -1.9498558244f,  1.8019377358f, -1.5636629649f,  1.2469796037f, -0.8677674782f,  0.4450418679f },
};

__global__ __launch_bounds__(256) void idct_conv_kernel(
    const float* __restrict__ X,
    const float* __restrict__ zf,
    float* __restrict__ out)
{
    int tid = blockIdx.x * 256 + threadIdx.x;
    if (tid >= NTOT) return;

    int x   = tid % WW;
    int rem = tid / WW;
    int y   = rem % HH;
    int b   = rem / HH;

    // last row/col are masked to zero in the reference
    if (y == HH - 1 || x == WW - 1) { out[tid] = 0.0f; return; }

    int i  = min(y, PP - 1);
    int j  = min(x, PP - 1);
    int dy = y - i;   // 0..6
    int dx = x - j;   // 0..6

    size_t base = ((size_t)b * HH + i) * WW + j;

    // 49 coefficients: [zf, X[0..47]]
    float c[49];
    c[0] = zf[base];
    const float4* xp = (const float4*)(X + base * NC); // 192-byte aligned
#pragma unroll
    for (int q = 0; q < 12; ++q) {
        float4 v = xp[q];
        c[1 + 4*q] = v.x;
        c[2 + 4*q] = v.y;
        c[3 + 4*q] = v.z;
        c[4 + 4*q] = v.w;
    }

    const float* wu = d_M[dy];
    const float* wv = d_M[dx];

    float acc = 0.0f;
#pragma unroll
    for (int u = 0; u < 7; ++u) {
        float s = 0.0f;
#pragma unroll
        for (int v = 0; v < 7; ++v)
            s = fmaf(wv[v], c[u * 7 + v], s);
        acc = fmaf(wu[u], s, acc);
    }

    out[tid] = acc;
}

extern "C" void kernel_launch(void* const* d_in, const int* in_sizes, int n_in,
                              void* d_out, int out_size, void* d_ws, size_t ws_size,
                              hipStream_t stream) {
    const float* X  = (const float*)d_in[0];   // (8,384,384,48) fp32
    const float* zf = (const float*)d_in[1];   // (8,384,384,1)  fp32
    float* out = (float*)d_out;                // (8,384,384,1)  fp32

    const int threads = 256;
    const int blocks  = (NTOT + threads - 1) / threads; // 4608
    idct_conv_kernel<<<blocks, threads, 0, stream>>>(X, zf, out);
}